// Round 6
// baseline (839.861 us; speedup 1.0000x reference)
//
#include <hip/hip_runtime.h>
#include <stdint.h>

#define NN 50000
#define NE 800000
#define DN 64
#define DEIN 192
#define DM 128
#define CAP 64          // bucket capacity (Poisson(16); P(>=64) negligible)
#define EB 64           // edge/node rows per tile
#define NB_SCAN 49      // ceil(NN/1024)
#define SENTN 0x7FFFFFFF

#define SA_STR 216      // 432B row stride: 2-way bank alias on b128 reads (free)
#define SX_STR 264

typedef __attribute__((ext_vector_type(4))) float f32x4;
typedef __attribute__((ext_vector_type(8))) short s16x8;

__device__ __forceinline__ unsigned short f2bf(float f) {
  union { float f; uint32_t u; } v; v.f = f;
  uint32_t u = v.u;
  u += 0x7FFF + ((u >> 16) & 1);   // RNE
  return (unsigned short)(u >> 16);
}
__device__ __forceinline__ float bf2f(unsigned short h) {
  union { uint32_t u; float f; } v; v.u = ((uint32_t)h) << 16;
  return v.f;
}
__device__ __forceinline__ ushort4 cvt4(float4 v) {
  ushort4 b; b.x = f2bf(v.x); b.y = f2bf(v.y); b.z = f2bf(v.z); b.w = f2bf(v.w);
  return b;
}

// ---- weight prep: bf16 [n][k]; reverse column-swap folded into B1rT
__global__ void kw2(const float* __restrict__ W1f, const float* __restrict__ W1r,
                    const float* __restrict__ W2f, const float* __restrict__ W2r,
                    const float* __restrict__ Wn1, const float* __restrict__ Wn2,
                    unsigned short* __restrict__ B1fT, unsigned short* __restrict__ B1rT,
                    unsigned short* __restrict__ B2T, unsigned short* __restrict__ Bn1T,
                    unsigned short* __restrict__ Bn2T) {
  int i = blockIdx.x * 256 + threadIdx.x;
  if (i < DM * DEIN) {
    int n = i / DEIN, k = i % DEIN;
    int pk = k < 64 ? k + 64 : (k < 128 ? k - 64 : k);
    B1fT[i] = f2bf(W1f[k * DM + n]);
    B1rT[i] = f2bf(W1r[pk * DM + n]);
    Bn1T[i] = f2bf(Wn1[k * DM + n]);
  }
  if (i < DM * 256) {
    int n = i / 256, k = i % 256;
    B2T[i] = f2bf(k < DM ? W2f[k * DM + n] : W2r[(k - DM) * DM + n]);
  }
  if (i < DN * DM) {
    int n = i / DM, k = i % DM;
    Bn2T[i] = f2bf(Wn2[k * DN + n]);
  }
}

// ---- bucket build
__global__ void kbucket(const int* __restrict__ tidx, const int* __restrict__ fidx,
                        int* __restrict__ cnt_to, int* __restrict__ cnt_from,
                        int* __restrict__ b_to, int* __restrict__ b_from) {
  int e = blockIdx.x * 256 + threadIdx.x;
  if (e >= NE) return;
  int t = tidx[e]; int s = atomicAdd(&cnt_to[t], 1);    if (s  < CAP) b_to[t * CAP + s]   = e;
  int f = fidx[e]; int s2 = atomicAdd(&cnt_from[f], 1); if (s2 < CAP) b_from[f * CAP + s2] = e;
}

// ---- prefix-sum stage 1: per-1024-block exclusive scan of clipped counts
__global__ void kscan1(const int* __restrict__ cnt, int* __restrict__ Ploc,
                       int* __restrict__ bsum) {
  __shared__ int s[1024];
  int tid = threadIdx.x, i = blockIdx.x * 1024 + tid;
  int c = 0;
  if (i < NN) { c = cnt[i]; if (c > CAP) c = CAP; }
  s[tid] = c;
  __syncthreads();
  for (int d = 1; d < 1024; d <<= 1) {
    int v = (tid >= d) ? s[tid - d] : 0;
    __syncthreads();
    s[tid] += v;
    __syncthreads();
  }
  if (i < NN) Ploc[i] = s[tid] - c;
  if (tid == 1023) bsum[blockIdx.x] = s[1023];
}

// ---- prefix-sum stage 2: scan the 49 block sums (trivial serial)
__global__ void kscan2(const int* __restrict__ bsum, int* __restrict__ boffs,
                       int* __restrict__ Rtot) {
  if (threadIdx.x == 0) {
    int acc = 0;
    for (int b = 0; b < NB_SCAN; b++) { boffs[b] = acc; acc += bsum[b]; }
    *Rtot = acc;
  }
}

// ---- scatter: sorted-by-destination edge list (edge id + owner node per row)
__global__ void kscatter(const int* __restrict__ cnt, const int* __restrict__ Ploc,
                         const int* __restrict__ boffs, const int* __restrict__ bucket,
                         int* __restrict__ sorted_e, int* __restrict__ sorted_n) {
  int i = blockIdx.x * 1024 + threadIdx.x;
  if (i >= NN) return;
  int c = cnt[i]; if (c > CAP) c = CAP;
  int base = Ploc[i] + boffs[i >> 10];
  for (int j = 0; j < c; j++) {
    sorted_e[base + j] = bucket[i * CAP + j];
    sorted_n[base + j] = i;
  }
}

// ---- fused edge-MLP + aggregation over destination-sorted edges.
// 512 threads = 8 waves; wave w owns output cols w*16..w*16+15; W1^T frags in
// regs; 64 sorted edges per block; node runs are contiguous -> in-register
// segmented column-sum; boundary segments via f32 atomicAdd, interior plain
// stores into memset-zeroed agg. No H materialization at all.
__launch_bounds__(512, 6)
__global__ void kfagg(const float* __restrict__ ns, const float* __restrict__ ef,
                      const int* __restrict__ fidx, const int* __restrict__ tidx,
                      const unsigned short* __restrict__ BT, const float* __restrict__ b1,
                      const int* __restrict__ sorted_e, const int* __restrict__ sorted_n,
                      const int* __restrict__ Rtot_p,
                      float* __restrict__ agg, int aoff) {
  __shared__ __align__(16) unsigned short sA[EB][SA_STR];
  __shared__ int snode[EB], seid[EB], sfi[EB], sti[EB];
  const int tid = threadIdx.x;
  const int w = tid >> 6, lane = tid & 63, g = lane >> 4, lr = lane & 15;
  const int nt = w;
  const int Rtot = *Rtot_p;
  const int grow0 = blockIdx.x * EB;
  if (grow0 >= Rtot) return;

  s16x8 bq[6];
#pragma unroll
  for (int kt = 0; kt < 6; kt++)
    bq[kt] = *(const s16x8*)&BT[(nt * 16 + lr) * DEIN + kt * 32 + g * 8];
  const float bv = b1[nt * 16 + lr];

  // phase 0: resolve rows (wave 0)
  if (tid < EB) {
    int grow = grow0 + tid;
    int n = SENTN, e = 0;
    if (grow < Rtot) { e = sorted_e[grow]; n = sorted_n[grow]; }
    snode[tid] = n; seid[tid] = e;
    sfi[tid] = fidx[e]; sti[tid] = tidx[e];
  }
  __syncthreads();

  // phase 1: stage A (8 threads per edge row: gather + cvt)
  {
    int row = tid >> 3, sub = tid & 7;
    bool val = snode[row] != SENTN;
    int e = seid[row], f = sfi[row], t = sti[row];
    const float4* pf = (const float4*)(ns + (size_t)f * DN);
    const float4* pt = (const float4*)(ns + (size_t)t * DN);
    const float4* pe = (const float4*)(ef + (size_t)e * DN);
    float4 z = {0.f, 0.f, 0.f, 0.f};
    float4 u0 = val ? pf[sub * 2] : z, u1 = val ? pf[sub * 2 + 1] : z;
    float4 u2 = val ? pt[sub * 2] : z, u3 = val ? pt[sub * 2 + 1] : z;
    float4 u4 = val ? pe[sub * 2] : z, u5 = val ? pe[sub * 2 + 1] : z;
    *(ushort4*)&sA[row][      sub * 8    ] = cvt4(u0);
    *(ushort4*)&sA[row][      sub * 8 + 4] = cvt4(u1);
    *(ushort4*)&sA[row][ 64 + sub * 8    ] = cvt4(u2);
    *(ushort4*)&sA[row][ 64 + sub * 8 + 4] = cvt4(u3);
    *(ushort4*)&sA[row][128 + sub * 8    ] = cvt4(u4);
    *(ushort4*)&sA[row][128 + sub * 8 + 4] = cvt4(u5);
  }
  __syncthreads();

  // phase 2: MFMA -> hidden values hv (row = m*16 + g*4 + r, col = nt*16+lr)
  float hv[16];
#pragma unroll
  for (int m = 0; m < 4; m++) {
    s16x8 a[6];
#pragma unroll
    for (int kt = 0; kt < 6; kt++)
      a[kt] = *(const s16x8*)&sA[m * 16 + lr][kt * 32 + g * 8];
    f32x4 c = {0.f, 0.f, 0.f, 0.f};
#pragma unroll
    for (int kt = 0; kt < 6; kt++)
      c = __builtin_amdgcn_mfma_f32_16x16x32_bf16(a[kt], bq[kt], c, 0, 0, 0);
#pragma unroll
    for (int r = 0; r < 4; r++) hv[m * 4 + r] = fmaxf(c[r] + bv, 0.f);
  }

  // phase 3: segmented column-sum over contiguous node runs
  int myn = snode[lane];
  int prevn = lane ? snode[lane - 1] : -1;
  unsigned long long mask = __ballot((lane == 0) || (myn != prevn));
  while (mask) {
    int ss = __builtin_ctzll(mask);
    mask &= mask - 1;
    int se = mask ? __builtin_ctzll(mask) : 64;
    int node = snode[ss];
    if (node == SENTN) break;              // sentinels are sorted last
    float p = 0.f;
#pragma unroll
    for (int m = 0; m < 4; m++)
#pragma unroll
      for (int r = 0; r < 4; r++) {
        int row = m * 16 + g * 4 + r;
        p += (row >= ss && row < se) ? hv[m * 4 + r] : 0.f;
      }
    p += __shfl_xor(p, 16);
    p += __shfl_xor(p, 32);
    if (g == 0) {
      float* dst = &agg[(size_t)node * 256 + aoff + nt * 16 + lr];
      if (ss == 0 || se == 64) atomicAdd(dst, p);   // run may span tiles
      else *dst = p;                                // run wholly inside tile
    }
  }
}

// ---- second layer as MFMA GEMM: msg = [aggF|aggR] @ [W2f;W2r] + cntT*b2f + cntF*b2r
__launch_bounds__(256, 2)
__global__ void kmm3(const float* __restrict__ agg, const unsigned short* __restrict__ B2T,
                     const float* __restrict__ b2f, const float* __restrict__ b2r,
                     const int* __restrict__ cnt_to, const int* __restrict__ cnt_from,
                     unsigned short* __restrict__ msg) {
  __shared__ __align__(16) unsigned short sX[2][EB][SX_STR];
  __shared__ float sb[2][DM];
  const int tid = threadIdx.x;
  const int w = tid >> 6, lane = tid & 63, g = lane >> 4, lr = lane & 15;
  if (tid < 2 * DM) sb[tid >> 7][tid & 127] = tid < DM ? b2f[tid] : b2r[tid - DM];

  s16x8 bq[2][8];
#pragma unroll
  for (int p = 0; p < 2; p++)
#pragma unroll
    for (int kt = 0; kt < 8; kt++)
      bq[p][kt] = *(const s16x8*)&B2T[((2 * w + p) * 16 + lr) * 256 + kt * 32 + g * 8];

  const int ntiles = (NN + EB - 1) / EB;
  auto stage = [&](int buf, int tile) {
    for (int i = tid; i < EB * 64; i += 256) {
      int rr = i >> 6, q = i & 63;
      int node = tile * EB + rr; if (node >= NN) node = NN - 1;
      float4 v = *((const float4*)(agg + (size_t)node * 256) + q);
      *(ushort4*)&sX[buf][rr][q * 4] = cvt4(v);
    }
  };
  int cur = 0;
  stage(0, blockIdx.x);
  __syncthreads();
  for (int t = blockIdx.x; t < ntiles; t += gridDim.x) {
    int tn = t + (int)gridDim.x;
    bool hn = tn < ntiles;
    if (hn) stage(cur ^ 1, tn);
    f32x4 acc[4][2];
#pragma unroll
    for (int m = 0; m < 4; m++) {
      s16x8 a[8];
#pragma unroll
      for (int kt = 0; kt < 8; kt++)
        a[kt] = *(const s16x8*)&sX[cur][m * 16 + lr][kt * 32 + g * 8];
#pragma unroll
      for (int p = 0; p < 2; p++) {
        f32x4 c = {0.f, 0.f, 0.f, 0.f};
#pragma unroll
        for (int kt = 0; kt < 8; kt++)
          c = __builtin_amdgcn_mfma_f32_16x16x32_bf16(a[kt], bq[p][kt], c, 0, 0, 0);
        acc[m][p] = c;
      }
    }
#pragma unroll
    for (int m = 0; m < 4; m++)
#pragma unroll
      for (int r = 0; r < 4; r++) {
        int node = t * EB + m * 16 + g * 4 + r;
        if (node < NN) {
          float cT = (float)cnt_to[node], cF = (float)cnt_from[node];
#pragma unroll
          for (int p = 0; p < 2; p++) {
            int cc = (2 * w + p) * 16 + lr;
            msg[(size_t)node * DM + cc] = f2bf(acc[m][p][r] + cT * sb[0][cc] + cF * sb[1][cc]);
          }
        }
      }
    __syncthreads();
    cur ^= 1;
  }
}

// ---- node MLP (two layers fused, MFMA) + residual
__launch_bounds__(256, 2)
__global__ void knode3(const unsigned short* __restrict__ msg, const float* __restrict__ ns,
                       const unsigned short* __restrict__ Bn1T, const unsigned short* __restrict__ Bn2T,
                       const float* __restrict__ bn1, const float* __restrict__ bn2,
                       float* __restrict__ out) {
  __shared__ __align__(16) unsigned short sX[2][EB][SA_STR];
  __shared__ __align__(16) unsigned short sH[EB][136];
  __shared__ float sb1[DM], sb2[DN];
  const int tid = threadIdx.x;
  const int w = tid >> 6, lane = tid & 63, g = lane >> 4, lr = lane & 15;
  if (tid < DM) sb1[tid] = bn1[tid];
  if (tid < DN) sb2[tid] = bn2[tid];

  s16x8 b1q[2][6], b2q[4];
#pragma unroll
  for (int p = 0; p < 2; p++)
#pragma unroll
    for (int kt = 0; kt < 6; kt++)
      b1q[p][kt] = *(const s16x8*)&Bn1T[((2 * w + p) * 16 + lr) * DEIN + kt * 32 + g * 8];
#pragma unroll
  for (int kt = 0; kt < 4; kt++)
    b2q[kt] = *(const s16x8*)&Bn2T[(w * 16 + lr) * DM + kt * 32 + g * 8];

  const int ntiles = (NN + EB - 1) / EB;
  auto stage = [&](int buf, int tile) {
    for (int i = tid; i < EB * 16; i += 256) {
      int rr = i >> 4, c8 = i & 15;
      int node = tile * EB + rr; if (node >= NN) node = NN - 1;
      *(int4*)&sX[buf][rr][c8 * 8] = *(const int4*)&msg[(size_t)node * DM + c8 * 8];
    }
    for (int i = tid; i < EB * 16; i += 256) {
      int rr = i >> 4, c4 = i & 15;
      int node = tile * EB + rr; if (node >= NN) node = NN - 1;
      float4 v = *((const float4*)(ns + (size_t)node * DN) + c4);
      *(ushort4*)&sX[buf][rr][DM + c4 * 4] = cvt4(v);
    }
  };
  int cur = 0;
  stage(0, blockIdx.x);
  __syncthreads();
  for (int t = blockIdx.x; t < ntiles; t += gridDim.x) {
    int tn = t + (int)gridDim.x;
    bool hn = tn < ntiles;
    if (hn) stage(cur ^ 1, tn);
    f32x4 acc1[4][2];
#pragma unroll
    for (int m = 0; m < 4; m++) {
      s16x8 a[6];
#pragma unroll
      for (int kt = 0; kt < 6; kt++)
        a[kt] = *(const s16x8*)&sX[cur][m * 16 + lr][kt * 32 + g * 8];
#pragma unroll
      for (int p = 0; p < 2; p++) {
        f32x4 c = {0.f, 0.f, 0.f, 0.f};
#pragma unroll
        for (int kt = 0; kt < 6; kt++)
          c = __builtin_amdgcn_mfma_f32_16x16x32_bf16(a[kt], b1q[p][kt], c, 0, 0, 0);
        acc1[m][p] = c;
      }
    }
    __syncthreads();
#pragma unroll
    for (int m = 0; m < 4; m++)
#pragma unroll
      for (int p = 0; p < 2; p++) {
        int cc = (2 * w + p) * 16 + lr;
#pragma unroll
        for (int r = 0; r < 4; r++)
          sH[m * 16 + g * 4 + r][cc] = f2bf(fmaxf(acc1[m][p][r] + sb1[cc], 0.f));
      }
    __syncthreads();
#pragma unroll
    for (int m = 0; m < 4; m++) {
      s16x8 a2[4];
#pragma unroll
      for (int kt = 0; kt < 4; kt++)
        a2[kt] = *(const s16x8*)&sH[m * 16 + lr][kt * 32 + g * 8];
      f32x4 c = {0.f, 0.f, 0.f, 0.f};
#pragma unroll
      for (int kt = 0; kt < 4; kt++)
        c = __builtin_amdgcn_mfma_f32_16x16x32_bf16(a2[kt], b2q[kt], c, 0, 0, 0);
      int col = w * 16 + lr;
#pragma unroll
      for (int r = 0; r < 4; r++) {
        int node = t * EB + m * 16 + g * 4 + r;
        if (node < NN)
          out[(size_t)node * DN + col] = ns[(size_t)node * DN + col] + c[r] + sb2[col];
      }
    }
    __syncthreads();
    cur ^= 1;
  }
}

extern "C" void kernel_launch(void* const* d_in, const int* in_sizes, int n_in,
                              void* d_out, int out_size, void* d_ws, size_t ws_size,
                              hipStream_t stream) {
  const float* ns  = (const float*)d_in[0];
  const float* ef  = (const float*)d_in[1];
  const float* W1f = (const float*)d_in[2];
  const float* b1f = (const float*)d_in[3];
  const float* W2f = (const float*)d_in[4];
  const float* b2f = (const float*)d_in[5];
  const float* W1r = (const float*)d_in[6];
  const float* b1r = (const float*)d_in[7];
  const float* W2r = (const float*)d_in[8];
  const float* b2r = (const float*)d_in[9];
  const float* Wn1 = (const float*)d_in[10];
  const float* bn1 = (const float*)d_in[11];
  const float* Wn2 = (const float*)d_in[12];
  const float* bn2 = (const float*)d_in[13];
  const int* fidx  = (const int*)d_in[14];
  const int* tidx  = (const int*)d_in[15];
  float* out = (float*)d_out;

  char* ws = (char*)d_ws;
  size_t off = 0;
  auto alloc = [&](size_t bytes) {
    off = (off + 255) & ~(size_t)255;
    void* p = ws + off; off += bytes; return p;
  };
  float* agg            = (float*)alloc((size_t)NN * 256 * 4);
  unsigned short* msg   = (unsigned short*)alloc((size_t)NN * DM * 2);
  int* b_to             = (int*)alloc((size_t)NN * CAP * 4);
  int* b_from           = (int*)alloc((size_t)NN * CAP * 4);
  int* cnt_to           = (int*)alloc((size_t)NN * 4);
  int* cnt_from         = (int*)alloc((size_t)NN * 4);
  int* Ploc_to          = (int*)alloc((size_t)NN * 4);
  int* Ploc_from        = (int*)alloc((size_t)NN * 4);
  int* se_to            = (int*)alloc((size_t)NE * 4);
  int* sn_to            = (int*)alloc((size_t)NE * 4);
  int* se_from          = (int*)alloc((size_t)NE * 4);
  int* sn_from          = (int*)alloc((size_t)NE * 4);
  int* bsum             = (int*)alloc((size_t)NB_SCAN * 4 * 2);
  int* boffs            = (int*)alloc((size_t)NB_SCAN * 4 * 2);
  int* Rtot             = (int*)alloc(2 * 4);
  unsigned short* B1fT  = (unsigned short*)alloc((size_t)DM * DEIN * 2);
  unsigned short* B1rT  = (unsigned short*)alloc((size_t)DM * DEIN * 2);
  unsigned short* B2T   = (unsigned short*)alloc((size_t)DM * 256 * 2);
  unsigned short* Bn1T  = (unsigned short*)alloc((size_t)DM * DEIN * 2);
  unsigned short* Bn2T  = (unsigned short*)alloc((size_t)DN * DM * 2);

  hipMemsetAsync(cnt_to, 0, (size_t)NN * 4, stream);
  hipMemsetAsync(cnt_from, 0, (size_t)NN * 4, stream);
  hipMemsetAsync(agg, 0, (size_t)NN * 256 * 4, stream);
  kw2<<<128, 256, 0, stream>>>(W1f, W1r, W2f, W2r, Wn1, Wn2, B1fT, B1rT, B2T, Bn1T, Bn2T);
  kbucket<<<(NE + 255) / 256, 256, 0, stream>>>(tidx, fidx, cnt_to, cnt_from, b_to, b_from);

  // counting sort by destination (per direction)
  kscan1<<<NB_SCAN, 1024, 0, stream>>>(cnt_to, Ploc_to, bsum);
  kscan2<<<1, 64, 0, stream>>>(bsum, boffs, Rtot);
  kscatter<<<NB_SCAN, 1024, 0, stream>>>(cnt_to, Ploc_to, boffs, b_to, se_to, sn_to);
  kscan1<<<NB_SCAN, 1024, 0, stream>>>(cnt_from, Ploc_from, bsum + NB_SCAN);
  kscan2<<<1, 64, 0, stream>>>(bsum + NB_SCAN, boffs + NB_SCAN, Rtot + 1);
  kscatter<<<NB_SCAN, 1024, 0, stream>>>(cnt_from, Ploc_from, boffs + NB_SCAN, b_from,
                                         se_from, sn_from);

  const int ntile_e = (NE + EB - 1) / EB;
  kfagg<<<ntile_e, 512, 0, stream>>>(ns, ef, fidx, tidx, B1fT, b1f,
                                     se_to, sn_to, Rtot, agg, 0);
  kfagg<<<ntile_e, 512, 0, stream>>>(ns, ef, fidx, tidx, B1rT, b1r,
                                     se_from, sn_from, Rtot + 1, agg, 128);

  int ntiles_n = (NN + EB - 1) / EB;
  kmm3<<<ntiles_n, 256, 0, stream>>>(agg, B2T, b2f, b2r, cnt_to, cnt_from, msg);
  knode3<<<ntiles_n, 256, 0, stream>>>(msg, ns, Bn1T, Bn2T, bn1, bn2, out);
}